// Round 2
// baseline (129.706 us; speedup 1.0000x reference)
//
#include <hip/hip_runtime.h>

#define THREADS 256
#define IMGS 8        // images per block (one 32-lane group per image)
#define N_PATCH 196
#define NCLS 10
#define FEAT 784      // 196 patches * 4 qubits = 28*28 pixels

__global__ __launch_bounds__(THREADS)
void quanv_fused_kernel(const float* __restrict__ x,
                        const float* __restrict__ U,
                        const float* __restrict__ W,
                        const float* __restrict__ b,
                        float* __restrict__ out,
                        int n_img)
{
    __shared__ float sU[256];           // 16x16 unitary, row-major U[e][d]
    const int t = threadIdx.x;
    sU[t] = U[t];
    __syncthreads();

    const int g    = t >> 5;            // image group 0..7
    const int lane = t & 31;
    const int img  = blockIdx.x * IMGS + g;
    if (img >= n_img) return;           // no further barriers below

    const float* ximg = x + (size_t)img * FEAT;

    float acc[NCLS];
#pragma unroll
    for (int c = 0; c < NCLS; ++c) acc[c] = 0.f;

    // ---- per-patch quantum feature + immediate linear-layer accumulation ----
    for (int p = lane; p < N_PATCH; p += 32) {
        const int r   = p / 14;
        const int col = p - r * 14;
        const float* px = ximg + r * 56 + col * 2;
        const float2 top = *(const float2*)px;          // x[2r][2c], x[2r][2c+1]
        const float2 bot = *(const float2*)(px + 28);   // x[2r+1][2c], x[2r+1][2c+1]

        float s0, c0, s1, c1, s2, c2, s3, c3;
        __sincosf(0.5f * top.x, &s0, &c0);
        __sincosf(0.5f * top.y, &s1, &c1);
        __sincosf(0.5f * bot.x, &s2, &c2);
        __sincosf(0.5f * bot.y, &s3, &c3);

        // product state, wire 0 = MSB: st[i*8+j*4+k*2+l] = a0[i]a1[j]a2[k]a3[l]
        const float p00 = c0 * c1, p01 = c0 * s1, p10 = s0 * c1, p11 = s0 * s1;
        const float q00 = c2 * c3, q01 = c2 * s3, q10 = s2 * c3, q11 = s2 * s3;
        float st[16];
        st[ 0] = p00 * q00; st[ 1] = p00 * q01; st[ 2] = p00 * q10; st[ 3] = p00 * q11;
        st[ 4] = p01 * q00; st[ 5] = p01 * q01; st[ 6] = p01 * q10; st[ 7] = p01 * q11;
        st[ 8] = p10 * q00; st[ 9] = p10 * q01; st[10] = p10 * q10; st[11] = p10 * q11;
        st[12] = p11 * q00; st[13] = p11 * q01; st[14] = p11 * q10; st[15] = p11 * q11;

        // amp_e = U[e]·st ; probs = amp^2 ; meas_q = sum_e zsign[e][q]*probs_e
        float m0 = 0.f, m1 = 0.f, m2 = 0.f, m3 = 0.f;
#pragma unroll
        for (int e = 0; e < 16; ++e) {
            const float4 u0 = *(const float4*)&sU[e * 16 + 0];
            const float4 u1 = *(const float4*)&sU[e * 16 + 4];
            const float4 u2 = *(const float4*)&sU[e * 16 + 8];
            const float4 u3 = *(const float4*)&sU[e * 16 + 12];
            // two independent 8-term halves -> shorter dep chains
            const float sa = u0.x * st[0]  + u0.y * st[1]  + u0.z * st[2]  + u0.w * st[3]
                           + u1.x * st[4]  + u1.y * st[5]  + u1.z * st[6]  + u1.w * st[7];
            const float sb = u2.x * st[8]  + u2.y * st[9]  + u2.z * st[10] + u2.w * st[11]
                           + u3.x * st[12] + u3.y * st[13] + u3.z * st[14] + u3.w * st[15];
            const float s  = sa + sb;
            const float sq = s * s;
            m0 += ((e >> 3) & 1) ? -sq : sq;    // wire 0 = MSB
            m1 += ((e >> 2) & 1) ? -sq : sq;
            m2 += ((e >> 1) & 1) ? -sq : sq;
            m3 += ((e >> 0) & 1) ? -sq : sq;
        }

        // fold the 4 features of this patch straight into the 10 class logits
#pragma unroll
        for (int c = 0; c < NCLS; ++c) {
            const float4 w = *(const float4*)&W[c * FEAT + p * 4];
            acc[c] += m0 * w.x + m1 * w.y + m2 * w.z + m3 * w.w;
        }
    }

    // ---- reduce partial logits across the 32-lane image group ----
#pragma unroll
    for (int c = 0; c < NCLS; ++c) {
        float v = acc[c];
        v += __shfl_xor(v, 16, 64);   // stays within each 32-lane half
        v += __shfl_xor(v,  8, 64);
        v += __shfl_xor(v,  4, 64);
        v += __shfl_xor(v,  2, 64);
        v += __shfl_xor(v,  1, 64);
        acc[c] = v + b[c];
    }

    // ---- log_softmax (all lanes redundantly; lanes 0..9 write) ----
    float m = acc[0];
#pragma unroll
    for (int c = 1; c < NCLS; ++c) m = fmaxf(m, acc[c]);
    float ssum = 0.f;
#pragma unroll
    for (int c = 0; c < NCLS; ++c) ssum += __expf(acc[c] - m);
    const float ls = __logf(ssum);

    float v = 0.f;
#pragma unroll
    for (int c = 0; c < NCLS; ++c) if (lane == c) v = acc[c];
    if (lane < NCLS)
        out[(size_t)img * NCLS + lane] = v - m - ls;
}

extern "C" void kernel_launch(void* const* d_in, const int* in_sizes, int n_in,
                              void* d_out, int out_size, void* d_ws, size_t ws_size,
                              hipStream_t stream) {
    const float* x = (const float*)d_in[0];
    const float* U = (const float*)d_in[1];
    const float* W = (const float*)d_in[2];
    const float* b = (const float*)d_in[3];
    float* out = (float*)d_out;

    const int n_img = in_sizes[0] / FEAT;           // 8192
    const int grid  = (n_img + IMGS - 1) / IMGS;    // 1024 blocks

    quanv_fused_kernel<<<grid, THREADS, 0, stream>>>(x, U, W, b, out, n_img);
}

// Round 5
// 123.828 us; speedup vs baseline: 1.0475x; 1.0475x over previous
//
#include <hip/hip_runtime.h>

#define THREADS 256
#define IMGS 8        // images per block (one 32-lane group per image)
#define N_PATCH 196
#define NCLS 10
#define FEAT 784      // 196 patches * 4 qubits = 28*28 pixels

__global__ __launch_bounds__(THREADS)
void quanv_fused_kernel(const float* __restrict__ x,
                        const float* __restrict__ U,   // 16x16 row-major; uniform-address -> s_load
                        const float* __restrict__ W,
                        const float* __restrict__ b,
                        float* __restrict__ out,
                        int n_img)
{
    const int t    = threadIdx.x;
    const int g    = t >> 5;            // image group 0..7
    const int lane = t & 31;
    const int img  = blockIdx.x * IMGS + g;
    if (img >= n_img) return;           // never taken at 8192 (8192 % 8 == 0)

    const float* ximg = x + (size_t)img * FEAT;

    float acc[NCLS];
#pragma unroll
    for (int c = 0; c < NCLS; ++c) acc[c] = 0.f;

    // Uniform trip count (7 for ALL lanes): keeps control flow uniform so the
    // compiler can scalarize the wave-uniform U loads (s_load, SMEM pipe).
    // Invalid lane-iterations (28 of 224) are predicated at the fold only.
#pragma unroll 1
    for (int it = 0; it < 7; ++it) {
        // Anti-LICM fence: without it the compiler hoists all 256 loop-
        // invariant U loads out of the p-loop (round 2: VGPR=172, occ 10%).
        asm volatile("" ::: "memory");

        const int p_raw = lane + 32 * it;
        const bool valid = (p_raw < N_PATCH);
        const int p = valid ? p_raw : N_PATCH - 1;   // clamp: safe in-bounds work

        const int r   = p / 14;
        const int col = p - r * 14;
        const float* px = ximg + r * 56 + col * 2;
        const float2 top = *(const float2*)px;          // x[2r][2c], x[2r][2c+1]
        const float2 bot = *(const float2*)(px + 28);   // x[2r+1][2c], x[2r+1][2c+1]

        float s0, c0, s1, c1, s2, c2, s3, c3;
        __sincosf(0.5f * top.x, &s0, &c0);
        __sincosf(0.5f * top.y, &s1, &c1);
        __sincosf(0.5f * bot.x, &s2, &c2);
        __sincosf(0.5f * bot.y, &s3, &c3);

        // product state, wire 0 = MSB: st[i*8+j*4+k*2+l] = a0[i]a1[j]a2[k]a3[l]
        const float p00 = c0 * c1, p01 = c0 * s1, p10 = s0 * c1, p11 = s0 * s1;
        const float q00 = c2 * c3, q01 = c2 * s3, q10 = s2 * c3, q11 = s2 * s3;
        float st[16];
        st[ 0] = p00 * q00; st[ 1] = p00 * q01; st[ 2] = p00 * q10; st[ 3] = p00 * q11;
        st[ 4] = p01 * q00; st[ 5] = p01 * q01; st[ 6] = p01 * q10; st[ 7] = p01 * q11;
        st[ 8] = p10 * q00; st[ 9] = p10 * q01; st[10] = p10 * q10; st[11] = p10 * q11;
        st[12] = p11 * q00; st[13] = p11 * q01; st[14] = p11 * q10; st[15] = p11 * q11;

        // amp_e = U[e]·st, sq_e = amp_e^2.  U address is wave-uniform with
        // compile-time offsets inside uniform CF -> s_load_dwordx16 per row,
        // v_fma with SGPR operand: zero per-lane VGPRs / zero VALU issue for U.
        float sq[16];
#pragma unroll
        for (int e = 0; e < 16; ++e) {
            float s = U[e * 16 + 0] * st[0];
#pragma unroll
            for (int j = 1; j < 16; ++j)
                s = fmaf(U[e * 16 + j], st[j], s);
            sq[e] = s * s;
        }

        // 4 PauliZ expectations = single-bit Walsh coefficients of sq[]
        // (shared partial sums: 40 ops instead of 64)
        float m3 = (sq[0]-sq[1]) + (sq[2]-sq[3]) + (sq[4]-sq[5]) + (sq[6]-sq[7])
                 + (sq[8]-sq[9]) + (sq[10]-sq[11]) + (sq[12]-sq[13]) + (sq[14]-sq[15]);
        float pr[8];
#pragma unroll
        for (int i = 0; i < 8; ++i) pr[i] = sq[2*i] + sq[2*i+1];
        float m2 = (pr[0]-pr[1]) + (pr[2]-pr[3]) + (pr[4]-pr[5]) + (pr[6]-pr[7]);
        const float q0 = pr[0]+pr[1], q1 = pr[2]+pr[3], q2 = pr[4]+pr[5], q3 = pr[6]+pr[7];
        float m1 = (q0 - q1) + (q2 - q3);
        float m0 = (q0 + q1) - (q2 + q3);

        // predicate the tail lanes out (4 mults instead of a divergent branch)
        const float wm = valid ? 1.0f : 0.0f;
        m0 *= wm; m1 *= wm; m2 *= wm; m3 *= wm;

        // fold the 4 features of this patch straight into the 10 class logits
#pragma unroll
        for (int c = 0; c < NCLS; ++c) {
            const float4 w = *(const float4*)&W[c * FEAT + p * 4];
            acc[c] += m0 * w.x + m1 * w.y + m2 * w.z + m3 * w.w;
        }
    }

    // ---- reduce partial logits across the 32-lane image group ----
#pragma unroll
    for (int c = 0; c < NCLS; ++c) {
        float v = acc[c];
        v += __shfl_xor(v, 16, 64);   // stays within each 32-lane half
        v += __shfl_xor(v,  8, 64);
        v += __shfl_xor(v,  4, 64);
        v += __shfl_xor(v,  2, 64);
        v += __shfl_xor(v,  1, 64);
        acc[c] = v + b[c];
    }

    // ---- log_softmax (all lanes redundantly; lanes 0..9 write) ----
    float m = acc[0];
#pragma unroll
    for (int c = 1; c < NCLS; ++c) m = fmaxf(m, acc[c]);
    float ssum = 0.f;
#pragma unroll
    for (int c = 0; c < NCLS; ++c) ssum += __expf(acc[c] - m);
    const float ls = __logf(ssum);

    float v = 0.f;
#pragma unroll
    for (int c = 0; c < NCLS; ++c) if (lane == c) v = acc[c];
    if (lane < NCLS)
        out[(size_t)img * NCLS + lane] = v - m - ls;
}

extern "C" void kernel_launch(void* const* d_in, const int* in_sizes, int n_in,
                              void* d_out, int out_size, void* d_ws, size_t ws_size,
                              hipStream_t stream) {
    const float* x = (const float*)d_in[0];
    const float* U = (const float*)d_in[1];
    const float* W = (const float*)d_in[2];
    const float* b = (const float*)d_in[3];
    float* out = (float*)d_out;

    const int n_img = in_sizes[0] / FEAT;           // 8192
    const int grid  = (n_img + IMGS - 1) / IMGS;    // 1024 blocks

    quanv_fused_kernel<<<grid, THREADS, 0, stream>>>(x, U, W, b, out, n_img);
}

// Round 6
// 118.236 us; speedup vs baseline: 1.0970x; 1.0473x over previous
//
#include <hip/hip_runtime.h>

#define THREADS 256
#define IMGS_PER_BLOCK 4   // one 64-lane wave per image
#define N_PATCH 196
#define NCLS 10
#define FEAT 784           // 196 patches * 4 qubits = 28*28 pixels

__global__ __launch_bounds__(THREADS)
void quanv_fused_kernel(const float* __restrict__ x,
                        const float* __restrict__ U,   // 16x16 row-major; uniform-address -> s_load
                        const float* __restrict__ W,
                        const float* __restrict__ b,
                        float* __restrict__ out,
                        int n_img)
{
    const int t    = threadIdx.x;
    const int wv   = t >> 6;            // wave id 0..3 == image slot in block
    const int lane = t & 63;
    const int img  = blockIdx.x * IMGS_PER_BLOCK + wv;
    if (img >= n_img) return;           // never taken at 8192

    const float* ximg = x + (size_t)img * FEAT;

    float acc[NCLS];
#pragma unroll
    for (int c = 0; c < NCLS; ++c) acc[c] = 0.f;

    // 4 uniform rounds over 64 lanes cover 196 patches (last round: 4 lanes).
    // Uniform CF keeps the wave-uniform U reads scalarized (s_load, SMEM pipe).
#pragma unroll 1
    for (int it = 0; it < 4; ++it) {
        // Anti-LICM fence: stops the compiler hoisting all 256 loop-invariant
        // U scalars out of the loop (round 2 pathology: VGPR=172, occ 10%).
        asm volatile("" ::: "memory");

        const int p_raw = lane + 64 * it;
        const bool valid = (p_raw < N_PATCH);
        const int p = valid ? p_raw : N_PATCH - 1;   // clamped in-bounds work

        const int r   = p / 14;
        const int col = p - r * 14;
        const float* px = ximg + r * 56 + col * 2;
        const float2 top = *(const float2*)px;          // x[2r][2c], x[2r][2c+1]
        const float2 bot = *(const float2*)(px + 28);   // x[2r+1][2c], x[2r+1][2c+1]

        // RY(theta)|0> = [cos(theta/2), sin(theta/2)]; native v_sin/v_cos
        const float h0 = 0.5f * top.x, h1 = 0.5f * top.y;
        const float h2 = 0.5f * bot.x, h3 = 0.5f * bot.y;
        const float c0 = __cosf(h0), s0 = __sinf(h0);
        const float c1 = __cosf(h1), s1 = __sinf(h1);
        const float c2 = __cosf(h2), s2 = __sinf(h2);
        const float c3 = __cosf(h3), s3 = __sinf(h3);

        // product state, wire 0 = MSB: st[i*8+j*4+k*2+l] = a0[i]a1[j]a2[k]a3[l]
        const float p00 = c0 * c1, p01 = c0 * s1, p10 = s0 * c1, p11 = s0 * s1;
        const float q00 = c2 * c3, q01 = c2 * s3, q10 = s2 * c3, q11 = s2 * s3;
        float st[16];
        st[ 0] = p00 * q00; st[ 1] = p00 * q01; st[ 2] = p00 * q10; st[ 3] = p00 * q11;
        st[ 4] = p01 * q00; st[ 5] = p01 * q01; st[ 6] = p01 * q10; st[ 7] = p01 * q11;
        st[ 8] = p10 * q00; st[ 9] = p10 * q01; st[10] = p10 * q10; st[11] = p10 * q11;
        st[12] = p11 * q00; st[13] = p11 * q01; st[14] = p11 * q10; st[15] = p11 * q11;

        // amp_e = U[e]·st (U via scalar loads: wave-uniform, compile-time
        // offsets). Process rows in PAIRS and fold squares immediately into
        // m3 / pr[] so only st[16]+pr[8]+m3 stay live (no sq[16] array ->
        // no spill/remat pressure at low VGPR counts).
        float m3 = 0.f;
        float pr[8];
#pragma unroll
        for (int i = 0; i < 8; ++i) {
            float sa = U[(2 * i) * 16]     * st[0];
            float sb = U[(2 * i + 1) * 16] * st[0];
#pragma unroll
            for (int j = 1; j < 16; ++j) {
                sa = fmaf(U[(2 * i) * 16 + j],     st[j], sa);
                sb = fmaf(U[(2 * i + 1) * 16 + j], st[j], sb);
            }
            const float qa = sa * sa;          // prob of basis 2i   (bit0 = 0)
            const float qb = sb * sb;          // prob of basis 2i+1 (bit0 = 1)
            m3   += qa - qb;                   // wire 3 = LSB
            pr[i] = qa + qb;
        }
        // remaining PauliZ expectations = Walsh sums over pr[]
        float m2 = (pr[0] - pr[1]) + (pr[2] - pr[3]) + (pr[4] - pr[5]) + (pr[6] - pr[7]);
        const float t0 = pr[0] + pr[1], t1 = pr[2] + pr[3];
        const float t2 = pr[4] + pr[5], t3 = pr[6] + pr[7];
        float m1 = (t0 - t1) + (t2 - t3);
        float m0 = (t0 + t1) - (t2 + t3);     // wire 0 = MSB

        // predicate tail lanes (4 mults, no divergent branch)
        const float wm = valid ? 1.0f : 0.0f;
        m0 *= wm; m1 *= wm; m2 *= wm; m3 *= wm;

        // fold this patch's 4 features straight into the 10 class logits
#pragma unroll
        for (int c = 0; c < NCLS; ++c) {
            const float4 w = *(const float4*)&W[c * FEAT + p * 4];
            acc[c] += m0 * w.x + m1 * w.y + m2 * w.z + m3 * w.w;
        }
    }

    // ---- reduce partial logits across the full 64-lane wave ----
#pragma unroll
    for (int c = 0; c < NCLS; ++c) {
        float v = acc[c];
        v += __shfl_xor(v, 32, 64);
        v += __shfl_xor(v, 16, 64);
        v += __shfl_xor(v,  8, 64);
        v += __shfl_xor(v,  4, 64);
        v += __shfl_xor(v,  2, 64);
        v += __shfl_xor(v,  1, 64);
        acc[c] = v + b[c];
    }

    // ---- log_softmax (all lanes redundantly; lanes 0..9 write) ----
    float m = acc[0];
#pragma unroll
    for (int c = 1; c < NCLS; ++c) m = fmaxf(m, acc[c]);
    float ssum = 0.f;
#pragma unroll
    for (int c = 0; c < NCLS; ++c) ssum += __expf(acc[c] - m);
    const float ls = __logf(ssum);

    float v = 0.f;
#pragma unroll
    for (int c = 0; c < NCLS; ++c) if (lane == c) v = acc[c];
    if (lane < NCLS)
        out[(size_t)img * NCLS + lane] = v - m - ls;
}

extern "C" void kernel_launch(void* const* d_in, const int* in_sizes, int n_in,
                              void* d_out, int out_size, void* d_ws, size_t ws_size,
                              hipStream_t stream) {
    const float* x = (const float*)d_in[0];
    const float* U = (const float*)d_in[1];
    const float* W = (const float*)d_in[2];
    const float* b = (const float*)d_in[3];
    float* out = (float*)d_out;

    const int n_img = in_sizes[0] / FEAT;                     // 8192
    const int grid  = (n_img + IMGS_PER_BLOCK - 1) / IMGS_PER_BLOCK;  // 2048 blocks

    quanv_fused_kernel<<<grid, THREADS, 0, stream>>>(x, U, W, b, out, n_img);
}

// Round 9
// 113.934 us; speedup vs baseline: 1.1384x; 1.0378x over previous
//
#include <hip/hip_runtime.h>

typedef __attribute__((ext_vector_type(8))) short short8;   // 8 bf16 = 4 VGPRs
typedef __attribute__((ext_vector_type(4))) float f32x4;

#define THREADS 256
#define WPB 4            // waves per block = images per block
#define N_PATCH 196
#define NCLS 10
#define FEAT 784
#define ROWSH 24         // ushort stride per LDS row = 48 B (16B-aligned, 2-way banks only)

union I4S8 { int i[4]; short8 v; };

__global__ __launch_bounds__(THREADS, 4)
void quanv_mfma_kernel(const float* __restrict__ x,
                       const float* __restrict__ U,
                       const float* __restrict__ W,
                       const float* __restrict__ b,
                       float* __restrict__ out, int n_img)
{
    // [wave][hi/lo][local patch 0..63][d 0..15 bf16 (+pad)]
    __shared__ unsigned short sB[WPB][2][64][ROWSH];

    const int t    = threadIdx.x;
    const int w    = t >> 6;
    const int lane = t & 63;
    const int img  = blockIdx.x * WPB + w;
    if (img >= n_img) return;                 // never taken at 8192; no barriers used

    const int colc = lane & 15;               // MFMA col (patch-in-group) / A row owner
    const int kb   = lane >> 4;               // k-block 0..3
    const float sgn0 = (kb & 2) ? -1.f : 1.f; // sign of e bit3 (wire 0, MSB)
    const float sgn1 = (kb & 1) ? -1.f : 1.f; // sign of e bit2 (wire 1)

    // ---- A fragments from U, loaded ONCE ----
    // A1 = [Uhi | Uhi], A2 = [Ulo | 0]  (16x32 each, K-blocked by lane>>4)
    short8 a1, a2;
    {
        const float* Urow = U + colc * 16 + (kb & 1) * 8;
        unsigned ub[8]; float uf[8];
#pragma unroll
        for (int i = 0; i < 8; ++i) { uf[i] = Urow[i]; ub[i] = __float_as_uint(uf[i]); }
        I4S8 hi, lo;
#pragma unroll
        for (int j = 0; j < 4; ++j)
            hi.i[j] = (int)__builtin_amdgcn_perm(ub[2*j+1], ub[2*j], 0x07060302u);
#pragma unroll
        for (int j = 0; j < 4; ++j) {
            unsigned lb0 = __float_as_uint(uf[2*j]   - __uint_as_float(ub[2*j]   & 0xffff0000u));
            unsigned lb1 = __float_as_uint(uf[2*j+1] - __uint_as_float(ub[2*j+1] & 0xffff0000u));
            lo.i[j] = (kb < 2) ? (int)__builtin_amdgcn_perm(lb1, lb0, 0x07060302u) : 0;
        }
        a1 = hi.v; a2 = lo.v;
    }

    const float* ximg = x + (size_t)img * FEAT;

    float acc[NCLS];
#pragma unroll
    for (int c = 0; c < NCLS; ++c) acc[c] = 0.f;

#pragma unroll 1
    for (int it = 0; it < 4; ++it) {
        // WAR fence: prior iteration's LDS reads drained before overwrite
        asm volatile("s_waitcnt lgkmcnt(0)" ::: "memory");

        // ---- build st[16] (fp32) for my patch ----
        const int pm    = it * 64 + lane;
        const bool vld  = (pm < N_PATCH);
        const int  pc   = vld ? pm : N_PATCH - 1;
        const int  r    = pc / 14;
        const int  cl   = pc - r * 14;
        const float* px = ximg + r * 56 + cl * 2;
        const float2 top = *(const float2*)px;
        const float2 bot = *(const float2*)(px + 28);

        const float c0 = __cosf(0.5f * top.x), s0 = __sinf(0.5f * top.x);
        const float c1 = __cosf(0.5f * top.y), s1 = __sinf(0.5f * top.y);
        const float c2 = __cosf(0.5f * bot.x), s2 = __sinf(0.5f * bot.x);
        const float c3 = __cosf(0.5f * bot.y), s3 = __sinf(0.5f * bot.y);

        const float wm = vld ? 1.f : 0.f;     // zero st => zero amp/meas for dead slots
        const float p00 = wm * c0 * c1, p01 = wm * c0 * s1;
        const float p10 = wm * s0 * c1, p11 = wm * s0 * s1;
        const float q00 = c2 * c3, q01 = c2 * s3, q10 = s2 * c3, q11 = s2 * s3;
        float st[16];
        st[ 0]=p00*q00; st[ 1]=p00*q01; st[ 2]=p00*q10; st[ 3]=p00*q11;
        st[ 4]=p01*q00; st[ 5]=p01*q01; st[ 6]=p01*q10; st[ 7]=p01*q11;
        st[ 8]=p10*q00; st[ 9]=p10*q01; st[10]=p10*q10; st[11]=p10*q11;
        st[12]=p11*q00; st[13]=p11*q01; st[14]=p11*q10; st[15]=p11*q11;

        // ---- exact split st = hi + lo, pack to bf16, stage to LDS ----
        I4S8 h0, h1, l0, l1;
#pragma unroll
        for (int j = 0; j < 8; ++j) {
            const unsigned b0 = __float_as_uint(st[2*j]);
            const unsigned b1 = __float_as_uint(st[2*j+1]);
            const unsigned hp = __builtin_amdgcn_perm(b1, b0, 0x07060302u);
            const unsigned lb0 = __float_as_uint(st[2*j]   - __uint_as_float(b0 & 0xffff0000u));
            const unsigned lb1 = __float_as_uint(st[2*j+1] - __uint_as_float(b1 & 0xffff0000u));
            const unsigned lp = __builtin_amdgcn_perm(lb1, lb0, 0x07060302u);
            if (j < 4) { h0.i[j] = (int)hp; l0.i[j] = (int)lp; }
            else       { h1.i[j-4] = (int)hp; l1.i[j-4] = (int)lp; }
        }
        *(short8*)&sB[w][0][lane][0] = h0.v;
        *(short8*)&sB[w][0][lane][8] = h1.v;
        *(short8*)&sB[w][1][lane][0] = l0.v;
        *(short8*)&sB[w][1][lane][8] = l1.v;

        asm volatile("s_waitcnt lgkmcnt(0)" ::: "memory");
        __builtin_amdgcn_sched_barrier(0);

        // ---- 4 groups of 16 patches: 2 MFMAs each, then Walsh + W-fold ----
#pragma unroll
        for (int g = 0; g < 4; ++g) {
            const int q = 16 * g + colc;                       // local patch (column)
            const unsigned short* src = (kb < 2) ? &sB[w][0][q][8 * (kb & 1)]
                                                 : &sB[w][1][q][8 * (kb & 1)];
            const short8 bf = *(const short8*)src;             // ds_read_b128

            f32x4 amv = {0.f, 0.f, 0.f, 0.f};
            amv = __builtin_amdgcn_mfma_f32_16x16x32_bf16(a1, bf, amv, 0, 0, 0);
            amv = __builtin_amdgcn_mfma_f32_16x16x32_bf16(a2, bf, amv, 0, 0, 0);

            // lane holds amp[e] for e = 4*kb + reg, patch = it*64 + q
            const float sq0 = amv[0]*amv[0], sq1 = amv[1]*amv[1];
            const float sq2 = amv[2]*amv[2], sq3 = amv[3]*amv[3];
            const float t01 = sq0 + sq1, t23 = sq2 + sq3, sall = t01 + t23;
            float m0 = sgn0 * sall;                    // wire0: (e&8) const per kb
            float m1 = sgn1 * sall;                    // wire1: (e&4)
            float m2 = t01 - t23;                      // wire2: (e&2) == reg&2
            float m3 = (sq0 - sq1) + (sq2 - sq3);      // wire3: (e&1) == reg&1

            // sum partial Walsh over the 4 k-blocks (same column)
            m0 += __shfl_xor(m0, 16, 64); m0 += __shfl_xor(m0, 32, 64);
            m1 += __shfl_xor(m1, 16, 64); m1 += __shfl_xor(m1, 32, 64);
            m2 += __shfl_xor(m2, 16, 64); m2 += __shfl_xor(m2, 32, 64);
            m3 += __shfl_xor(m3, 16, 64); m3 += __shfl_xor(m3, 32, 64);

            // fold into logits (replicated across kb; final reduce avoids recount)
            const int pg  = it * 64 + q;
            const int pcl = (pg < N_PATCH) ? pg : N_PATCH - 1; // m's are 0 when invalid
#pragma unroll
            for (int c = 0; c < NCLS; ++c) {
                const float4 wv = *(const float4*)&W[c * FEAT + 4 * pcl];
                acc[c] = fmaf(m0, wv.x, fmaf(m1, wv.y, fmaf(m2, wv.z, fmaf(m3, wv.w, acc[c]))));
            }
        }
    }

    // ---- reduce logits over the 16 columns only (xor 1,2,4,8):
    // kb-replicas are identical and NOT summed (no double count).
#pragma unroll
    for (int c = 0; c < NCLS; ++c) {
        float v = acc[c];
        v += __shfl_xor(v, 1, 64);
        v += __shfl_xor(v, 2, 64);
        v += __shfl_xor(v, 4, 64);
        v += __shfl_xor(v, 8, 64);
        acc[c] = v + b[c];
    }

    // ---- log_softmax ----
    float m = acc[0];
#pragma unroll
    for (int c = 1; c < NCLS; ++c) m = fmaxf(m, acc[c]);
    float ssum = 0.f;
#pragma unroll
    for (int c = 0; c < NCLS; ++c) ssum += __expf(acc[c] - m);
    const float ls = __logf(ssum);

    float v = 0.f;
#pragma unroll
    for (int c = 0; c < NCLS; ++c) if (lane == c) v = acc[c];
    if (lane < NCLS)
        out[(size_t)img * NCLS + lane] = v - m - ls;
}

extern "C" void kernel_launch(void* const* d_in, const int* in_sizes, int n_in,
                              void* d_out, int out_size, void* d_ws, size_t ws_size,
                              hipStream_t stream) {
    const float* x = (const float*)d_in[0];
    const float* U = (const float*)d_in[1];
    const float* W = (const float*)d_in[2];
    const float* b = (const float*)d_in[3];
    float* out = (float*)d_out;

    const int n_img = in_sizes[0] / FEAT;            // 8192
    const int grid  = (n_img + WPB - 1) / WPB;       // 2048 blocks

    quanv_mfma_kernel<<<grid, THREADS, 0, stream>>>(x, U, W, b, out, n_img);
}